// Round 1
// 408.163 us; speedup vs baseline: 1.0112x; 1.0112x over previous
//
#include <hip/hip_runtime.h>
#include <hip/hip_bf16.h>

// LSTM cell: B=4096, IN=1024, H=2048.
// gates = [prev_h | x] @ [W_i;W_f;W_o;W_c]^T  -> [4096, 8192]
// R6: 256x256-tile GEMM, 8 waves (2x4), BK=32, 4 LDS buffers (128 KiB),
// prefetch depth 3 with counted vmcnt(8) (never 0 in main loop),
// 2 phases/K-tile with setprio around MFMA clusters, rotation-swizzled LDS
// (pre-swizzled global source, rule 21), bijective XCD block swizzle.
// pack_all / lstm_ep unchanged from R5.

#define BATCH 4096
#define INW   1024
#define HID   2048
#define GK    3072   // HID + INW
#define GN    8192   // 4*HID

typedef __attribute__((ext_vector_type(8))) short short8;
typedef __attribute__((ext_vector_type(4))) float floatx4;

__device__ __forceinline__ unsigned short f2bf(float f) {
    union { float f; unsigned u; } v; v.f = f;
    unsigned r = v.u + 0x7FFFu + ((v.u >> 16) & 1u);
    return (unsigned short)(r >> 16);
}
__device__ __forceinline__ float bf2f(unsigned short u) {
    union { unsigned u; float f; } v; v.u = ((unsigned)u) << 16;
    return v.f;
}
__device__ __forceinline__ float sigf(float x) {
    return 1.0f / (1.0f + __expf(-x));
}
__device__ __forceinline__ float tanhfast(float x) {
    float t = __expf(fminf(fmaxf(2.0f * x, -30.0f), 30.0f));
    return (t - 1.0f) / (t + 1.0f);
}

// ---- single pack kernel: each thread converts 8 fp32 -> 8 bf16 ----
__global__ __launch_bounds__(256) void pack_all(const float4* __restrict__ ph,
                                                const float4* __restrict__ x,
                                                const float4* __restrict__ Wi,
                                                const float4* __restrict__ Wf,
                                                const float4* __restrict__ Wo,
                                                const float4* __restrict__ Wc,
                                                unsigned short* __restrict__ hx,
                                                unsigned short* __restrict__ Wb) {
    long i = (long)blockIdx.x * 256 + threadIdx.x;
    const float4* src;
    unsigned short* dst;
    if (i < 1048576L) {            // prev_h [4096,2048] -> hx[:, 0:2048]
        int r  = (int)(i >> 8);
        int c8 = (int)(i & 255);
        src = ph + 2 * i;
        dst = hx + (size_t)r * GK + (size_t)c8 * 8;
    } else if (i < 1572864L) {     // x [4096,1024] -> hx[:, 2048:3072]
        long j = i - 1048576L;
        int r  = (int)(j >> 7);
        int c8 = (int)(j & 127);
        src = x + 2 * j;
        dst = hx + (size_t)r * GK + HID + (size_t)c8 * 8;
    } else {                        // W_g [2048,3072] -> Wb + g*HID*GK
        long j = i - 1572864L;
        const float4* Wg;
        int g;
        if (j < 786432L)            { Wg = Wi; g = 0; }
        else if (j < 1572864L)      { Wg = Wf; g = 1; j -= 786432L; }
        else if (j < 2359296L)      { Wg = Wo; g = 2; j -= 1572864L; }
        else                        { Wg = Wc; g = 3; j -= 2359296L; }
        src = Wg + 2 * j;
        dst = Wb + (size_t)g * HID * GK + (size_t)j * 8;
    }
    float4 v0 = src[0];
    float4 v1 = src[1];
    unsigned short o[8];
    o[0] = f2bf(v0.x); o[1] = f2bf(v0.y); o[2] = f2bf(v0.z); o[3] = f2bf(v0.w);
    o[4] = f2bf(v1.x); o[5] = f2bf(v1.y); o[6] = f2bf(v1.z); o[7] = f2bf(v1.w);
    *(short8*)dst = *(const short8*)o;
}

__device__ __forceinline__ void gld16(const unsigned short* g, unsigned short* l) {
    __builtin_amdgcn_global_load_lds((const __attribute__((address_space(1))) unsigned int*)g,
                                     (__attribute__((address_space(3))) unsigned int*)l,
                                     16, 0, 0);
}

template<int VM> __device__ __forceinline__ void wait_vm() {
    if constexpr (VM == 8)      asm volatile("s_waitcnt vmcnt(8)" ::: "memory");
    else if constexpr (VM == 4) asm volatile("s_waitcnt vmcnt(4)" ::: "memory");
    else if constexpr (VM == 0) asm volatile("s_waitcnt vmcnt(0)" ::: "memory");
    // VM == -1: no wait (final iteration)
}

// ---- C[M,N] = A[M,K] * Bt[N,K]^T  (bf16 in, bf16 out, fp32 acc) ----
// 256x256 tile, 512 threads (8 waves, 2M x 4N), BK=32, 4 LDS tile-buffers.
// LDS per tile per matrix: 256 rows x 32 bf16 = 16 KB; 4 chunk-slots of 8 bf16/row.
// Rotation swizzle: slot s of row r holds global k-chunk c with s = (c + (r>>1)) & 3
//  -> ds_read_b128 (16 rows x 4 k-chunks per wave) hits every bank exactly twice (free).
// Staging (global_load_lds, linear dest): thread t, load l covers row l*128 + (t>>2),
// slot t&3, global chunk c0 = ((t&3) - ((t>>3)&3)) & 3 (invariant across l since 128>>1 = 64 ≡ 0 mod 4).
// Pipeline: buffers t&3; iteration t computes tile t, stages tile t+3 into buf[(t+3)&3]
// = buf[(t-1)&3] (freed at end of iteration t-1 -> race-free); trailing s_waitcnt
// vmcnt(8) drains tile t+1 only (tiles t+2, t+3 = 8 loads stay in flight).
__global__ __launch_bounds__(512, 2) void gemm_bt(const unsigned short* __restrict__ A,
                                                  const unsigned short* __restrict__ Bt,
                                                  unsigned short* __restrict__ C) {
    __shared__ unsigned short lds[65536];   // 128 KiB: A bufs [0,32768), B bufs [32768,65536)
    const int tid  = threadIdx.x;
    const int wave = tid >> 6;
    const int lane = tid & 63;

    // bijective XCD swizzle (512 blocks, 512 % 8 == 0); N-major so each XCD
    // keeps 2 A-panels (2 x 1.5 MB) L2-resident while streaming B.
    const int bid = blockIdx.x;
    const int swz = ((bid & 7) << 6) + (bid >> 3);
    const long row0 = (long)(swz >> 5) * 256;   // 16 M-tiles
    const long col0 = (long)(swz & 31) * 256;   // 32 N-tiles

    const int wm = wave >> 2;   // 0..1 -> rows wm*128
    const int wn = wave & 3;    // 0..3 -> cols wn*64

    // staging source pointers (pre-swizzled chunk)
    const int c0 = ((tid & 3) - ((tid >> 3) & 3)) & 3;
    const unsigned short* gA0 = A  + (row0 + (tid >> 2)) * GK + c0 * 8;
    const unsigned short* gB0 = Bt + (col0 + (tid >> 2)) * GK + c0 * 8;

#define STAGE_A(kt, b) do { \
        unsigned short* _d = &lds[(b) * 8192 + tid * 8]; \
        gld16(gA0 + (size_t)(kt) * 32, _d); \
        gld16(gA0 + 128 * GK + (size_t)(kt) * 32, _d + 4096); \
    } while (0)
#define STAGE_B(kt, b) do { \
        unsigned short* _d = &lds[32768 + (b) * 8192 + tid * 8]; \
        gld16(gB0 + (size_t)(kt) * 32, _d); \
        gld16(gB0 + 128 * GK + (size_t)(kt) * 32, _d + 4096); \
    } while (0)

    // fragment read offsets (ushort units)
    const int fr = lane & 15;
    const int cq = lane >> 4;                       // k-chunk 0..3 (BK=32)
    const int slot = ((cq + (fr >> 1)) & 3) << 3;
    const int aoff = (wm * 128 + fr) * 32 + slot;   // + mi*512, phase1 +2048
    const int boff = (wn * 64 + fr) * 32 + slot;    // + nj*512

    floatx4 acc[8][4];
    #pragma unroll
    for (int i = 0; i < 8; i++)
        #pragma unroll
        for (int j = 0; j < 4; j++)
            acc[i][j] = (floatx4)(0.0f);

    // prologue: stage tiles 0,1,2 (12 loads); drain tile 0 (vmcnt(8) leaves tiles 1,2 in flight)
    STAGE_A(0, 0); STAGE_B(0, 0);
    STAGE_A(1, 1); STAGE_B(1, 1);
    STAGE_A(2, 2); STAGE_B(2, 2);
    asm volatile("s_waitcnt vmcnt(8)" ::: "memory");
    __builtin_amdgcn_s_barrier();

#define K_ITER(t, VMW, STG) do { \
        const unsigned short* bufA = &lds[((t) & 3) * 8192]; \
        const unsigned short* bufB = &lds[32768 + ((t) & 3) * 8192]; \
        short8 af[4], bfv[4]; \
        /* phase 0: read A m0-3 + B n0-3, stage A of tile t+3, MFMA quadrant m0-3 */ \
        _Pragma("unroll") \
        for (int i = 0; i < 4; i++) af[i]  = *(const short8*)&bufA[aoff + i * 512]; \
        _Pragma("unroll") \
        for (int j = 0; j < 4; j++) bfv[j] = *(const short8*)&bufB[boff + j * 512]; \
        if (STG) { STAGE_A((t) + 3, ((t) + 3) & 3); } \
        __builtin_amdgcn_s_barrier(); \
        asm volatile("s_waitcnt lgkmcnt(0)" ::: "memory"); \
        __builtin_amdgcn_sched_barrier(0); \
        __builtin_amdgcn_s_setprio(1); \
        _Pragma("unroll") \
        for (int i = 0; i < 4; i++) \
            _Pragma("unroll") \
            for (int j = 0; j < 4; j++) \
                acc[i][j] = __builtin_amdgcn_mfma_f32_16x16x32_bf16(af[i], bfv[j], acc[i][j], 0, 0, 0); \
        __builtin_amdgcn_s_setprio(0); \
        __builtin_amdgcn_s_barrier(); \
        /* phase 1: read A m4-7 (B frags reused), stage B of tile t+3, MFMA quadrant m4-7 */ \
        _Pragma("unroll") \
        for (int i = 0; i < 4; i++) af[i] = *(const short8*)&bufA[aoff + 2048 + i * 512]; \
        if (STG) { STAGE_B((t) + 3, ((t) + 3) & 3); } \
        __builtin_amdgcn_s_barrier(); \
        asm volatile("s_waitcnt lgkmcnt(0)" ::: "memory"); \
        __builtin_amdgcn_sched_barrier(0); \
        __builtin_amdgcn_s_setprio(1); \
        _Pragma("unroll") \
        for (int i = 0; i < 4; i++) \
            _Pragma("unroll") \
            for (int j = 0; j < 4; j++) \
                acc[4 + i][j] = __builtin_amdgcn_mfma_f32_16x16x32_bf16(af[i], bfv[j], acc[4 + i][j], 0, 0, 0); \
        __builtin_amdgcn_s_setprio(0); \
        wait_vm<VMW>(); \
        __builtin_amdgcn_s_barrier(); \
    } while (0)

    // main loop: 96 K-tiles of 32. t < 93 stages tile t+3 (last staged = 95).
    int t = 0;
    for (; t < 93; ++t) K_ITER(t, 8, true);
    K_ITER(93, 4, false);   // drain tile 94 (tile 95 stays in flight)
    K_ITER(94, 0, false);   // drain tile 95 (epilogue only)
    K_ITER(95, -1, false);

#undef K_ITER
#undef STAGE_A
#undef STAGE_B

    // C/D layout: col = lane&15, row = (lane>>4)*4 + reg  [m89-verified]
    const int cr = (lane >> 4) << 2;
    const int cc = lane & 15;
    #pragma unroll
    for (int mi = 0; mi < 8; mi++) {
        #pragma unroll
        for (int nj = 0; nj < 4; nj++) {
            long base = (row0 + wm * 128 + mi * 16 + cr) * (long)GN + col0 + wn * 64 + nj * 16 + cc;
            #pragma unroll
            for (int r = 0; r < 4; r++)
                C[base + (long)r * GN] = f2bf(acc[mi][nj][r]);
        }
    }
}

// ---- LSTM elementwise epilogue: gates[B,4H] bf16 (i,f,o,c slabs) -> FP32 next_h, next_c ----
__global__ __launch_bounds__(256) void lstm_ep(const unsigned short* __restrict__ gates,
                                               const float* __restrict__ prev_c,
                                               float* __restrict__ out) {
    const int i = blockIdx.x * 256 + threadIdx.x;
    const int b = i >> 9;
    const int h = (i & 511) << 2;
    const size_t gb = (size_t)b * GN + h;
    ushort4 gi = *(const ushort4*)&gates[gb];
    ushort4 gf = *(const ushort4*)&gates[gb + HID];
    ushort4 go = *(const ushort4*)&gates[gb + 2 * HID];
    ushort4 gc = *(const ushort4*)&gates[gb + 3 * HID];
    const size_t ob = (size_t)b * HID + h;
    float4 c4 = *(const float4*)&prev_c[ob];

    unsigned short giv[4] = {gi.x, gi.y, gi.z, gi.w};
    unsigned short gfv[4] = {gf.x, gf.y, gf.z, gf.w};
    unsigned short gov[4] = {go.x, go.y, go.z, go.w};
    unsigned short gcv[4] = {gc.x, gc.y, gc.z, gc.w};
    float cv[4] = {c4.x, c4.y, c4.z, c4.w};
    float nh[4], nc[4];
    #pragma unroll
    for (int j = 0; j < 4; j++) {
        float vi = sigf(bf2f(giv[j]));
        float vf = sigf(bf2f(gfv[j]));
        float vo = sigf(bf2f(gov[j]));
        float vc = tanhfast(bf2f(gcv[j]));
        float ncf = vf * cv[j] + vi * vc;
        float nhf = vo * tanhfast(ncf);
        nc[j] = ncf;
        nh[j] = nhf;
    }
    float4 vh = {nh[0], nh[1], nh[2], nh[3]};
    float4 vc4 = {nc[0], nc[1], nc[2], nc[3]};
    *(float4*)&out[ob] = vh;
    *(float4*)&out[(size_t)BATCH * HID + ob] = vc4;
}

extern "C" void kernel_launch(void* const* d_in, const int* in_sizes, int n_in,
                              void* d_out, int out_size, void* d_ws, size_t ws_size,
                              hipStream_t stream) {
    const float* x   = (const float*)d_in[0];
    const float* ph  = (const float*)d_in[1];
    const float* pc  = (const float*)d_in[2];
    const float* Wi  = (const float*)d_in[3];
    const float* Wf  = (const float*)d_in[4];
    const float* Wo  = (const float*)d_in[5];
    const float* Wc  = (const float*)d_in[6];

    // workspace (bf16): hx [4096,3072] | Wb [8192,3072] | gates [4096,8192]  (~143 MB)
    unsigned short* hx    = (unsigned short*)d_ws;
    unsigned short* Wb    = hx + (size_t)BATCH * GK;
    unsigned short* gates = Wb + (size_t)GN * GK;
    float* out = (float*)d_out;

    pack_all<<<18432, 256, 0, stream>>>((const float4*)ph, (const float4*)x,
                                        (const float4*)Wi, (const float4*)Wf,
                                        (const float4*)Wo, (const float4*)Wc,
                                        hx, Wb);

    gemm_bt<<<512, 512, 0, stream>>>(hx, Wb, gates);

    lstm_ep<<<(BATCH * HID / 4) / 256, 256, 0, stream>>>(gates, pc, out);
}